// Round 4
// baseline (564.583 us; speedup 1.0000x reference)
//
#include <hip/hip_runtime.h>
#include <math.h>

#define NCLU 196
#define DIM  256
#define DV4  (DIM / 4)
#define TEMPERATURE 0.5f
#define EPSV 1e-12f
#define TPB  256
#define NWAVES 4
#define SPLIT 8      // gather blocks per cluster
#define BATCH 8      // samples per wave batch (16 dwordx4 in flight)
#define HBLK 256     // histogram blocks
#define SBLK 256     // scatter blocks

// ---- block reduction helpers (256 threads = 4 waves of 64) ----
__device__ inline float blockReduceSum(float v, volatile float* sbuf) {
#pragma unroll
  for (int off = 32; off >= 1; off >>= 1) v += __shfl_xor(v, off, 64);
  const int lane = threadIdx.x & 63;
  const int wv   = threadIdx.x >> 6;
  __syncthreads();
  if (lane == 0) sbuf[wv] = v;
  __syncthreads();
  return sbuf[0] + sbuf[1] + sbuf[2] + sbuf[3];
}

__device__ inline float blockReduceMax(float v, volatile float* sbuf) {
#pragma unroll
  for (int off = 32; off >= 1; off >>= 1) v = fmaxf(v, __shfl_xor(v, off, 64));
  const int lane = threadIdx.x & 63;
  const int wv   = threadIdx.x >> 6;
  __syncthreads();
  if (lane == 0) sbuf[wv] = v;
  __syncthreads();
  return fmaxf(fmaxf(sbuf[0], sbuf[1]), fmaxf(sbuf[2], sbuf[3]));
}

// ---- K0: global histogram of labels ----
__global__ __launch_bounds__(TPB) void k_hist(const int* __restrict__ lab, int n,
                                              int* __restrict__ ghist) {
  __shared__ int lh[NCLU];
  for (int i = threadIdx.x; i < NCLU; i += TPB) lh[i] = 0;
  __syncthreads();
  const int4* l4 = (const int4*)lab;
  const int n4 = n >> 2;
  for (int i = blockIdx.x * TPB + threadIdx.x; i < n4; i += gridDim.x * TPB) {
    const int4 v = l4[i];
    atomicAdd(&lh[v.x], 1); atomicAdd(&lh[v.y], 1);
    atomicAdd(&lh[v.z], 1); atomicAdd(&lh[v.w], 1);
  }
  __syncthreads();
  for (int i = threadIdx.x; i < NCLU; i += TPB)
    if (lh[i]) atomicAdd(&ghist[i], lh[i]);
}

// ---- K0b: parallel exclusive scan (one block, Hillis-Steele in LDS) ----
__global__ __launch_bounds__(TPB) void k_scan(const int* __restrict__ ghist,
                                              int* __restrict__ offsets,
                                              int* __restrict__ gcursor) {
  __shared__ int a[TPB], b[TPB];
  const int t = threadIdx.x;
  const int v = (t < NCLU) ? ghist[t] : 0;
  a[t] = v;
  __syncthreads();
  int* src = a; int* dst = b;
#pragma unroll
  for (int off = 1; off < TPB; off <<= 1) {
    dst[t] = src[t] + ((t >= off) ? src[t - off] : 0);
    __syncthreads();
    int* tmp = src; src = dst; dst = tmp;
  }
  if (t < NCLU) {
    const int excl = src[t] - v;     // inclusive -> exclusive
    offsets[t] = excl;
    gcursor[t] = excl;
  }
}

// ---- K1: counting-sort sample indices by label (two-pass LDS ticketing) ----
__global__ __launch_bounds__(TPB) void k_scatter(const int* __restrict__ lab, int n,
                                                 int* __restrict__ gcursor,
                                                 int* __restrict__ order) {
  __shared__ int lh[NCLU];
  __shared__ int lbase[NCLU];
  const int chunk = (n + gridDim.x - 1) / gridDim.x;
  const int start = blockIdx.x * chunk;
  const int end = min(n, start + chunk);
  for (int i = threadIdx.x; i < NCLU; i += TPB) lh[i] = 0;
  __syncthreads();
  for (int s = start + threadIdx.x; s < end; s += TPB) atomicAdd(&lh[lab[s]], 1);
  __syncthreads();
  for (int i = threadIdx.x; i < NCLU; i += TPB) {
    const int c = lh[i];
    lbase[i] = c ? atomicAdd(&gcursor[i], c) : 0;
  }
  __syncthreads();
  for (int i = threadIdx.x; i < NCLU; i += TPB) lh[i] = 0;   // reuse as local cursor
  __syncthreads();
  for (int s = start + threadIdx.x; s < end; s += TPB) {
    const int c = lab[s];
    const int p = atomicAdd(&lh[c], 1);
    order[lbase[c] + p] = s;
  }
}

// ---- K2: register-blocked gather-reduce; 16 dwordx4 in flight per wave ----
__global__ __launch_bounds__(TPB) void k_gather(
    const float* __restrict__ q, const float* __restrict__ k,
    const int* __restrict__ order, const int* __restrict__ offsets,
    const int* __restrict__ ghist,
    float* __restrict__ gsq, float* __restrict__ gsk) {
  const int c = blockIdx.x, p = blockIdx.y;
  const int base = offsets[c];
  const int len = ghist[c];
  const int lo = (int)(((long)len * p) / SPLIT);
  const int hi = (int)(((long)len * (p + 1)) / SPLIT);
  const int cnt = hi - lo;
  if (cnt <= 0) return;                       // block-uniform, no barriers below

  const int lane = threadIdx.x & 63;
  const int w = threadIdx.x >> 6;             // 0..3
  const int* __restrict__ ord = order + base + lo;
  const float4* __restrict__ q4 = (const float4*)q + lane;
  const float4* __restrict__ k4 = (const float4*)k + lane;

  float4 aq = make_float4(0.f, 0.f, 0.f, 0.f);
  float4 ak = make_float4(0.f, 0.f, 0.f, 0.f);

  const int nb = cnt / BATCH;                 // full batches, interleaved over waves
  for (int b = w; b < nb; b += NWAVES) {
    const int s0 = b * BATCH;
    int idx[BATCH];
#pragma unroll
    for (int j = 0; j < BATCH; ++j) idx[j] = ord[s0 + j];   // uniform -> s_load
    float4 vq[BATCH], vk[BATCH];
#pragma unroll
    for (int j = 0; j < BATCH; ++j) {
      vq[j] = q4[(long)idx[j] * DV4];
      vk[j] = k4[(long)idx[j] * DV4];
    }
#pragma unroll
    for (int j = 0; j < BATCH; ++j) {
      aq.x += vq[j].x; aq.y += vq[j].y; aq.z += vq[j].z; aq.w += vq[j].w;
      ak.x += vk[j].x; ak.y += vk[j].y; ak.z += vk[j].z; ak.w += vk[j].w;
    }
  }
  if (w == 0) {                               // tail (< BATCH samples)
    for (int i = nb * BATCH; i < cnt; ++i) {
      const int idx = ord[i];
      const float4 vq = q4[(long)idx * DV4];
      const float4 vk = k4[(long)idx * DV4];
      aq.x += vq.x; aq.y += vq.y; aq.z += vq.z; aq.w += vq.w;
      ak.x += vk.x; ak.y += vk.y; ak.z += vk.z; ak.w += vk.w;
    }
  }

  const int o = c * DIM + lane * 4;
  atomicAdd(&gsq[o + 0], aq.x); atomicAdd(&gsq[o + 1], aq.y);
  atomicAdd(&gsq[o + 2], aq.z); atomicAdd(&gsq[o + 3], aq.w);
  atomicAdd(&gsk[o + 0], ak.x); atomicAdd(&gsk[o + 1], ak.y);
  atomicAdd(&gsk[o + 2], ak.z); atomicAdd(&gsk[o + 3], ak.w);
}

// ---- K3: centers = normalize(sums/counts); transposed copy + d_k ----
__global__ __launch_bounds__(TPB) void k_centers(
    const float* __restrict__ gsq, const float* __restrict__ gsk,
    const int* __restrict__ gcnt,
    float* __restrict__ qc, float* __restrict__ kc,
    float* __restrict__ qcT, float* __restrict__ dk) {
  __shared__ float sbuf[4];
  const int c = blockIdx.x, t = threadIdx.x;   // t indexes dim (DIM == TPB)
  const float denom = fmaxf((float)gcnt[c], EPSV);
  const float sq = gsq[c * DIM + t] / denom;
  const float sk = gsk[c * DIM + t] / denom;
  const float nq = blockReduceSum(sq * sq, sbuf);
  const float nk = blockReduceSum(sk * sk, sbuf);
  const float qv = sq / fmaxf(sqrtf(nq), EPSV);
  const float kv = sk / fmaxf(sqrtf(nk), EPSV);
  qc[c * DIM + t] = qv;
  kc[c * DIM + t] = kv;
  qcT[t * NCLU + c] = qv;
  const float dot = blockReduceSum(qv * kv, sbuf);
  if (t == 0) dk[c] = dot / TEMPERATURE;
}

// ---- K4: per-row similarity + masked logsumexp -> row loss ----
__global__ __launch_bounds__(TPB) void k_rowloss(
    const float* __restrict__ qc, const float* __restrict__ qcT,
    const float* __restrict__ dk, const int* __restrict__ gcnt,
    float* __restrict__ rowloss) {
  __shared__ float qrow[DIM];
  __shared__ float sbuf[4];
  const int c = blockIdx.x, t = threadIdx.x;
  qrow[t] = qc[c * DIM + t];
  __syncthreads();

  float v = -INFINITY;
  if (t < NCLU) {
    float dot = 0.f;
#pragma unroll 8
    for (int d = 0; d < DIM; ++d) dot += qrow[d] * qcT[d * NCLU + t];
    v = dot * (1.0f / TEMPERATURE);       // /0.5 == *2.0, exact
    if (t == c) v = dk[c];                // diag <- d_k (already /T)
    if (gcnt[t] == 0) v = -10.f;          // column mask AFTER diag set
  }
  const float m    = blockReduceMax(v, sbuf);
  const float e    = (t < NCLU) ? expf(v - m) : 0.f;
  const float ssum = blockReduceSum(e, sbuf);
  if (t == 0) {
    float loss = 0.f;
    if (gcnt[c] != 0) loss = -dk[c] + m + logf(ssum);
    rowloss[c] = loss;
  }
}

// ---- K5: final scalar ----
__global__ __launch_bounds__(TPB) void k_final(
    const float* __restrict__ rowloss, const int* __restrict__ gcnt,
    float* __restrict__ out) {
  __shared__ float sbuf[4];
  const int t = threadIdx.x;
  const float ls = (t < NCLU) ? rowloss[t] : 0.f;
  const float nz = (t < NCLU && gcnt[t] == 0) ? 1.f : 0.f;
  const float total = blockReduceSum(ls, sbuf);
  const float nzero = blockReduceSum(nz, sbuf);
  if (t == 0) out[0] = total / ((float)NCLU - nzero);
}

extern "C" void kernel_launch(void* const* d_in, const int* in_sizes, int n_in,
                              void* d_out, int out_size, void* d_ws, size_t ws_size,
                              hipStream_t stream) {
  const float* q  = (const float*)d_in[0];
  const float* k  = (const float*)d_in[1];
  const int* lab  = (const int*)d_in[2];
  const int n = in_sizes[0] / DIM;

  float* gsq      = (float*)d_ws;           // NCLU*DIM f32
  float* gsk      = gsq + NCLU * DIM;       // NCLU*DIM f32
  int*   ghist    = (int*)(gsk + NCLU * DIM);   // NCLU (end of zeroed region)
  int*   offsets  = ghist + NCLU;           // NCLU (written by k_scan)
  int*   gcursor  = offsets + NCLU;         // NCLU (written by k_scan)
  int*   order    = gcursor + NCLU;         // n
  float* qc       = (float*)(order + n);    // NCLU*DIM
  float* kc       = qc + NCLU * DIM;        // NCLU*DIM
  float* qcT      = kc + NCLU * DIM;        // DIM*NCLU
  float* dk       = qcT + DIM * NCLU;       // NCLU
  float* rowloss  = dk + NCLU;              // NCLU

  // Zero accumulators (gsq, gsk, ghist are contiguous).
  hipMemsetAsync(d_ws, 0,
                 (size_t)(2 * NCLU * DIM) * sizeof(float) + NCLU * sizeof(int),
                 stream);

  k_hist   <<<HBLK, TPB, 0, stream>>>(lab, n, ghist);
  k_scan   <<<1, TPB, 0, stream>>>(ghist, offsets, gcursor);
  k_scatter<<<SBLK, TPB, 0, stream>>>(lab, n, gcursor, order);
  dim3 g2(NCLU, SPLIT);
  k_gather <<<g2, TPB, 0, stream>>>(q, k, order, offsets, ghist, gsq, gsk);
  k_centers<<<NCLU, TPB, 0, stream>>>(gsq, gsk, ghist, qc, kc, qcT, dk);
  k_rowloss<<<NCLU, TPB, 0, stream>>>(qc, qcT, dk, ghist, rowloss);
  k_final  <<<1, TPB, 0, stream>>>(rowloss, ghist, (float*)d_out);
}

// Round 5
// 560.055 us; speedup vs baseline: 1.0081x; 1.0081x over previous
//
#include <hip/hip_runtime.h>
#include <math.h>

#define NCLU 196
#define DIM  256
#define DV4  (DIM / 4)
#define TEMPERATURE 0.5f
#define EPSV 1e-12f
#define TPB  256
#define NWAVES 4
#define SPLIT 8      // gather blocks per cluster
#define BATCH 8      // samples per wave batch -> 16 dwordx4 in flight (asm)
#define HBLK 256     // histogram blocks
#define SBLK 256     // scatter blocks

typedef float f32x4_t __attribute__((ext_vector_type(4)));

// ---- block reduction helpers (256 threads = 4 waves of 64) ----
__device__ inline float blockReduceSum(float v, volatile float* sbuf) {
#pragma unroll
  for (int off = 32; off >= 1; off >>= 1) v += __shfl_xor(v, off, 64);
  const int lane = threadIdx.x & 63;
  const int wv   = threadIdx.x >> 6;
  __syncthreads();
  if (lane == 0) sbuf[wv] = v;
  __syncthreads();
  return sbuf[0] + sbuf[1] + sbuf[2] + sbuf[3];
}

__device__ inline float blockReduceMax(float v, volatile float* sbuf) {
#pragma unroll
  for (int off = 32; off >= 1; off >>= 1) v = fmaxf(v, __shfl_xor(v, off, 64));
  const int lane = threadIdx.x & 63;
  const int wv   = threadIdx.x >> 6;
  __syncthreads();
  if (lane == 0) sbuf[wv] = v;
  __syncthreads();
  return fmaxf(fmaxf(sbuf[0], sbuf[1]), fmaxf(sbuf[2], sbuf[3]));
}

// ---- K0: global histogram of labels ----
__global__ __launch_bounds__(TPB) void k_hist(const int* __restrict__ lab, int n,
                                              int* __restrict__ ghist) {
  __shared__ int lh[NCLU];
  for (int i = threadIdx.x; i < NCLU; i += TPB) lh[i] = 0;
  __syncthreads();
  const int4* l4 = (const int4*)lab;
  const int n4 = n >> 2;
  for (int i = blockIdx.x * TPB + threadIdx.x; i < n4; i += gridDim.x * TPB) {
    const int4 v = l4[i];
    atomicAdd(&lh[v.x], 1); atomicAdd(&lh[v.y], 1);
    atomicAdd(&lh[v.z], 1); atomicAdd(&lh[v.w], 1);
  }
  __syncthreads();
  for (int i = threadIdx.x; i < NCLU; i += TPB)
    if (lh[i]) atomicAdd(&ghist[i], lh[i]);
}

// ---- K0b: parallel exclusive scan (one block, Hillis-Steele in LDS) ----
__global__ __launch_bounds__(TPB) void k_scan(const int* __restrict__ ghist,
                                              int* __restrict__ offsets,
                                              int* __restrict__ gcursor) {
  __shared__ int a[TPB], b[TPB];
  const int t = threadIdx.x;
  const int v = (t < NCLU) ? ghist[t] : 0;
  a[t] = v;
  __syncthreads();
  int* src = a; int* dst = b;
#pragma unroll
  for (int off = 1; off < TPB; off <<= 1) {
    dst[t] = src[t] + ((t >= off) ? src[t - off] : 0);
    __syncthreads();
    int* tmp = src; src = dst; dst = tmp;
  }
  if (t < NCLU) {
    const int excl = src[t] - v;     // inclusive -> exclusive
    offsets[t] = excl;
    gcursor[t] = excl;
  }
}

// ---- K1: counting-sort sample indices by label (two-pass LDS ticketing) ----
__global__ __launch_bounds__(TPB) void k_scatter(const int* __restrict__ lab, int n,
                                                 int* __restrict__ gcursor,
                                                 int* __restrict__ order) {
  __shared__ int lh[NCLU];
  __shared__ int lbase[NCLU];
  const int chunk = (n + gridDim.x - 1) / gridDim.x;
  const int start = blockIdx.x * chunk;
  const int end = min(n, start + chunk);
  for (int i = threadIdx.x; i < NCLU; i += TPB) lh[i] = 0;
  __syncthreads();
  for (int s = start + threadIdx.x; s < end; s += TPB) atomicAdd(&lh[lab[s]], 1);
  __syncthreads();
  for (int i = threadIdx.x; i < NCLU; i += TPB) {
    const int c = lh[i];
    lbase[i] = c ? atomicAdd(&gcursor[i], c) : 0;
  }
  __syncthreads();
  for (int i = threadIdx.x; i < NCLU; i += TPB) lh[i] = 0;   // reuse as local cursor
  __syncthreads();
  for (int s = start + threadIdx.x; s < end; s += TPB) {
    const int c = lab[s];
    const int p = atomicAdd(&lh[c], 1);
    order[lbase[c] + p] = s;
  }
}

// ---- K2: gather-reduce; inline-asm batch keeps 16 dwordx4 in flight ----
__global__ __launch_bounds__(TPB) void k_gather(
    const float* __restrict__ q, const float* __restrict__ k,
    const int* __restrict__ order, const int* __restrict__ offsets,
    const int* __restrict__ ghist,
    float* __restrict__ gsq, float* __restrict__ gsk) {
  const int c = blockIdx.x, p = blockIdx.y;
  const int base = offsets[c];
  const int len = ghist[c];
  const int lo = (int)(((long)len * p) / SPLIT);
  const int hi = (int)(((long)len * (p + 1)) / SPLIT);
  const int cnt = hi - lo;
  if (cnt <= 0) return;                       // block-uniform, no barriers below

  const int lane = threadIdx.x & 63;
  const int w = threadIdx.x >> 6;             // 0..3
  const int* __restrict__ ord = order + base + lo;
  const char* qb = (const char*)q + (size_t)lane * 16;   // this lane's 16B column
  const char* kb = (const char*)k + (size_t)lane * 16;

  f32x4_t aq = {0.f, 0.f, 0.f, 0.f};
  f32x4_t ak = {0.f, 0.f, 0.f, 0.f};

  const int nb = cnt / BATCH;                 // full batches, interleaved over waves
  for (int b = w; b < nb; b += NWAVES) {
    const int s0 = b * BATCH;
    long off[BATCH];
#pragma unroll
    for (int j = 0; j < BATCH; ++j) off[j] = (long)ord[s0 + j] << 10;  // *1024 B/row
    f32x4_t vq[BATCH], vk[BATCH];
    // Issue all 16 loads back-to-back; volatile asm cannot be sunk by the
    // compiler, so they stay outstanding together (real MLP).
#pragma unroll
    for (int j = 0; j < BATCH; ++j) {
      asm volatile("global_load_dwordx4 %0, %1, off"
                   : "=&v"(vq[j]) : "v"(qb + off[j]));
      asm volatile("global_load_dwordx4 %0, %1, off"
                   : "=&v"(vk[j]) : "v"(kb + off[j]));
    }
    asm volatile("s_waitcnt vmcnt(0)" ::: "memory");
    __builtin_amdgcn_sched_barrier(0);        // rule #18: pin consumers below wait
#pragma unroll
    for (int j = 0; j < BATCH; ++j) { aq += vq[j]; ak += vk[j]; }
  }
  if (w == 0) {                               // tail (< BATCH samples)
    const f32x4_t* q4 = (const f32x4_t*)qb;
    const f32x4_t* k4 = (const f32x4_t*)kb;
    for (int i = nb * BATCH; i < cnt; ++i) {
      const long idx = ord[i];
      aq += q4[idx * DV4];
      ak += k4[idx * DV4];
    }
  }

  const int o = c * DIM + lane * 4;
  atomicAdd(&gsq[o + 0], aq.x); atomicAdd(&gsq[o + 1], aq.y);
  atomicAdd(&gsq[o + 2], aq.z); atomicAdd(&gsq[o + 3], aq.w);
  atomicAdd(&gsk[o + 0], ak.x); atomicAdd(&gsk[o + 1], ak.y);
  atomicAdd(&gsk[o + 2], ak.z); atomicAdd(&gsk[o + 3], ak.w);
}

// ---- K3: centers = normalize(sums/counts); transposed copy + d_k ----
__global__ __launch_bounds__(TPB) void k_centers(
    const float* __restrict__ gsq, const float* __restrict__ gsk,
    const int* __restrict__ gcnt,
    float* __restrict__ qc, float* __restrict__ kc,
    float* __restrict__ qcT, float* __restrict__ dk) {
  __shared__ float sbuf[4];
  const int c = blockIdx.x, t = threadIdx.x;   // t indexes dim (DIM == TPB)
  const float denom = fmaxf((float)gcnt[c], EPSV);
  const float sq = gsq[c * DIM + t] / denom;
  const float sk = gsk[c * DIM + t] / denom;
  const float nq = blockReduceSum(sq * sq, sbuf);
  const float nk = blockReduceSum(sk * sk, sbuf);
  const float qv = sq / fmaxf(sqrtf(nq), EPSV);
  const float kv = sk / fmaxf(sqrtf(nk), EPSV);
  qc[c * DIM + t] = qv;
  kc[c * DIM + t] = kv;
  qcT[t * NCLU + c] = qv;
  const float dot = blockReduceSum(qv * kv, sbuf);
  if (t == 0) dk[c] = dot / TEMPERATURE;
}

// ---- K4: per-row similarity + masked logsumexp -> row loss ----
__global__ __launch_bounds__(TPB) void k_rowloss(
    const float* __restrict__ qc, const float* __restrict__ qcT,
    const float* __restrict__ dk, const int* __restrict__ gcnt,
    float* __restrict__ rowloss) {
  __shared__ float qrow[DIM];
  __shared__ float sbuf[4];
  const int c = blockIdx.x, t = threadIdx.x;
  qrow[t] = qc[c * DIM + t];
  __syncthreads();

  float v = -INFINITY;
  if (t < NCLU) {
    float dot = 0.f;
#pragma unroll 8
    for (int d = 0; d < DIM; ++d) dot += qrow[d] * qcT[d * NCLU + t];
    v = dot * (1.0f / TEMPERATURE);       // /0.5 == *2.0, exact
    if (t == c) v = dk[c];                // diag <- d_k (already /T)
    if (gcnt[t] == 0) v = -10.f;          // column mask AFTER diag set
  }
  const float m    = blockReduceMax(v, sbuf);
  const float e    = (t < NCLU) ? expf(v - m) : 0.f;
  const float ssum = blockReduceSum(e, sbuf);
  if (t == 0) {
    float loss = 0.f;
    if (gcnt[c] != 0) loss = -dk[c] + m + logf(ssum);
    rowloss[c] = loss;
  }
}

// ---- K5: final scalar ----
__global__ __launch_bounds__(TPB) void k_final(
    const float* __restrict__ rowloss, const int* __restrict__ gcnt,
    float* __restrict__ out) {
  __shared__ float sbuf[4];
  const int t = threadIdx.x;
  const float ls = (t < NCLU) ? rowloss[t] : 0.f;
  const float nz = (t < NCLU && gcnt[t] == 0) ? 1.f : 0.f;
  const float total = blockReduceSum(ls, sbuf);
  const float nzero = blockReduceSum(nz, sbuf);
  if (t == 0) out[0] = total / ((float)NCLU - nzero);
}

extern "C" void kernel_launch(void* const* d_in, const int* in_sizes, int n_in,
                              void* d_out, int out_size, void* d_ws, size_t ws_size,
                              hipStream_t stream) {
  const float* q  = (const float*)d_in[0];
  const float* k  = (const float*)d_in[1];
  const int* lab  = (const int*)d_in[2];
  const int n = in_sizes[0] / DIM;

  float* gsq      = (float*)d_ws;           // NCLU*DIM f32
  float* gsk      = gsq + NCLU * DIM;       // NCLU*DIM f32
  int*   ghist    = (int*)(gsk + NCLU * DIM);   // NCLU (end of zeroed region)
  int*   offsets  = ghist + NCLU;           // NCLU (written by k_scan)
  int*   gcursor  = offsets + NCLU;         // NCLU (written by k_scan)
  int*   order    = gcursor + NCLU;         // n
  float* qc       = (float*)(order + n);    // NCLU*DIM
  float* kc       = qc + NCLU * DIM;        // NCLU*DIM
  float* qcT      = kc + NCLU * DIM;        // DIM*NCLU
  float* dk       = qcT + DIM * NCLU;       // NCLU
  float* rowloss  = dk + NCLU;              // NCLU

  // Zero accumulators (gsq, gsk, ghist are contiguous).
  hipMemsetAsync(d_ws, 0,
                 (size_t)(2 * NCLU * DIM) * sizeof(float) + NCLU * sizeof(int),
                 stream);

  k_hist   <<<HBLK, TPB, 0, stream>>>(lab, n, ghist);
  k_scan   <<<1, TPB, 0, stream>>>(ghist, offsets, gcursor);
  k_scatter<<<SBLK, TPB, 0, stream>>>(lab, n, gcursor, order);
  dim3 g2(NCLU, SPLIT);
  k_gather <<<g2, TPB, 0, stream>>>(q, k, order, offsets, ghist, gsq, gsk);
  k_centers<<<NCLU, TPB, 0, stream>>>(gsq, gsk, ghist, qc, kc, qcT, dk);
  k_rowloss<<<NCLU, TPB, 0, stream>>>(qc, qcT, dk, ghist, rowloss);
  k_final  <<<1, TPB, 0, stream>>>(rowloss, ghist, (float*)d_out);
}